// Round 10
// baseline (152.087 us; speedup 1.0000x reference)
//
#include <hip/hip_runtime.h>

typedef float f32x4 __attribute__((ext_vector_type(4)));

#define B 256
#define D 256
#define N 200000
#define C 1000

#define K1_BLOCKS   2048
#define LOGITS_LO   0      // 256 blocks: logits
#define NEWROWS_LO  256    // 256 blocks: new_rows
#define TOUCH_BLK   512    // 1 block: touched marks
#define HIST_LO     513    // 64 blocks: LDS-privatized label histogram
#define HIST_BLOCKS 64
#define COPY_LO     577    // 1471 blocks: streaming copy
#define COPY_BLOCKS (K1_BLOCKS - COPY_LO)

// ---------------- ws layout (bytes) ----------------
#define WS_NEWROWS_OFF  0          // B*D f32 = 262144
#define WS_HIST_OFF     262144     // C int = 4000   (zeroed region start)
#define WS_TOUCHED_OFF  266144     // C int = 4000
#define WS_NW_OFF       270144     // 1 int          (zeroed region end)
#define WS_OFFS_OFF     270148     // C int = 4000
#define WS_FILLPOS_OFF  274148     // C int = 4000
#define WS_WROW_OFF     278148     // B int = 1024
#define WS_WLAB_OFF     279172     // B int = 1024
#define WS_WB_OFF       280196     // B int = 1024
#define WS_ROWLIST_OFF  281220     // N int = 800000 -> total 1,081,220
#define ZERO_WORDS      (2 * C + 1)  // hist + touched + nw (contiguous)

// K0: zero hist + touched + nw (ws is poisoned 0xAA, never re-poisoned)
__global__ __launch_bounds__(256) void k0_zero(int* __restrict__ z) {
    int i = blockIdx.x * 256 + threadIdx.x;
    if (i < ZERO_WORDS) z[i] = 0;
}

// K1: logits (0..255) || new_rows (256..511) || touched (512) || hist (513..576)
//     || streaming copy features->out_feats (577..2047).
//     Copy uses PLAIN cached loads + PLAIN stores: every NT variant (R6-R9) and
//     the SDMA blit all plateaued at 2.1-3.0 TB/s, while reg+reg copy is the
//     m13-verified 6.29 TB/s pattern and the harness fill (reg stores) hits 7.
__global__ __launch_bounds__(256) void k1_kernel(
    const float* __restrict__ inputs, const float* __restrict__ features,
    const float* __restrict__ cluster_mean, const int* __restrict__ indexes,
    const int* __restrict__ labels, const int* __restrict__ targets,
    float* __restrict__ out_logits, float* __restrict__ out_feats,
    float* __restrict__ new_rows, int* __restrict__ hist, int* __restrict__ touched)
{
    const int blk = blockIdx.x;
    const int t = threadIdx.x;

    if (blk >= COPY_LO) {
        // ---- bulk copy, ILP-4, plain loads + plain stores ----
        const f32x4* src = (const f32x4*)features;
        f32x4*       dst = (f32x4*)out_feats;
        const int total4 = N * (D / 4);            // 12,800,000
        const int stride = COPY_BLOCKS * 256;      // 376,576
        int i = (blk - COPY_LO) * 256 + t;
        for (; i + 3 * stride < total4; i += 4 * stride) {
            f32x4 v0 = src[i];
            f32x4 v1 = src[i + stride];
            f32x4 v2 = src[i + 2 * stride];
            f32x4 v3 = src[i + 3 * stride];
            dst[i] = v0;
            dst[i + stride] = v1;
            dst[i + 2 * stride] = v2;
            dst[i + 3 * stride] = v3;
        }
        for (; i < total4; i += stride)
            dst[i] = src[i];
    } else if (blk < NEWROWS_LO) {
        // ---- logits[b,:] = inputs[b] @ cluster_mean.T ----
        __shared__ float sbuf[D];
        int b = blk - LOGITS_LO;
        sbuf[t] = inputs[b * D + t];
        __syncthreads();
        const f32x4* cmv = (const f32x4*)cluster_mean;
        for (int c = t; c < C; c += 256) {
            const f32x4* cm = cmv + (size_t)c * 64;
            float a0 = 0.f, a1 = 0.f, a2 = 0.f, a3 = 0.f;
            #pragma unroll 8
            for (int d4 = 0; d4 < 64; ++d4) {
                f32x4 v = cm[d4];
                const float* si = sbuf + d4 * 4;
                a0 += v.x * si[0];
                a1 += v.y * si[1];
                a2 += v.z * si[2];
                a3 += v.w * si[3];
            }
            out_logits[(size_t)b * C + c] = (a0 + a1) + (a2 + a3);
        }
    } else if (blk < TOUCH_BLK) {
        // ---- new_rows[b] = l2norm(0.5*features[indexes[b]] + 0.5*inputs[b]) ----
        __shared__ float wpart[4];
        __shared__ float stot;
        int b = blk - NEWROWS_LO;
        int r = indexes[b];
        float x = 0.5f * features[(size_t)r * D + t] + 0.5f * inputs[b * D + t];
        float s = x * x;
        #pragma unroll
        for (int off = 32; off > 0; off >>= 1) s += __shfl_down(s, off);
        if ((t & 63) == 0) wpart[t >> 6] = s;
        __syncthreads();
        if (t == 0) stot = (wpart[0] + wpart[1]) + (wpart[2] + wpart[3]);
        __syncthreads();
        new_rows[b * D + t] = x / sqrtf(stot + 1e-12f);
    } else if (blk == TOUCH_BLK) {
        if (t < B) touched[targets[t]] = 1;
    } else {
        // ---- label histogram, LDS-privatized ----
        __shared__ int lh[C];
        for (int i = t; i < C; i += 256) lh[i] = 0;
        __syncthreads();
        const int stride = HIST_BLOCKS * 256;
        for (int i = (blk - HIST_LO) * 256 + t; i < N; i += stride)
            atomicAdd(&lh[labels[i]], 1);
        __syncthreads();
        for (int i = t; i < C; i += 256) {
            int v = lh[i];
            if (v) atomicAdd(&hist[i], v);
        }
    }
}

// K2: patch winner rows into out_feats + append winner metadata (blk 0..255)
//     || prefix scan (blk 256)
__global__ __launch_bounds__(256) void k2_kernel(
    const int* __restrict__ indexes, const int* __restrict__ labels,
    const float* __restrict__ new_rows, float* __restrict__ out_feats,
    const int* __restrict__ hist, int* __restrict__ offs, int* __restrict__ fillpos,
    int* __restrict__ nw, int* __restrict__ w_row, int* __restrict__ w_lab,
    int* __restrict__ w_b)
{
    const int blk = blockIdx.x;
    const int t = threadIdx.x;

    if (blk < 256) {
        // last-write-wins: block b writes row indexes[b] iff no j>b shares it.
        __shared__ int sidx[B];
        __shared__ int lose;
        sidx[t] = indexes[t];
        if (t == 0) lose = 0;
        __syncthreads();
        int b = blk;
        int my = sidx[b];
        if (t > b && sidx[t] == my) lose = 1;
        __syncthreads();
        if (!lose) {
            out_feats[(size_t)my * D + t] = new_rows[b * D + t];
            if (t == 0) {
                int p = atomicAdd(nw, 1);
                w_row[p] = my;
                w_lab[p] = labels[my];
                w_b[p] = b;
            }
        }
    } else {
        // exclusive prefix scan of hist -> offs, fillpos (256 thr x 4 bins)
        __shared__ int swt[4];
        int base = t * 4;
        int h0 = (base + 0 < C) ? hist[base + 0] : 0;
        int h1 = (base + 1 < C) ? hist[base + 1] : 0;
        int h2 = (base + 2 < C) ? hist[base + 2] : 0;
        int h3 = (base + 3 < C) ? hist[base + 3] : 0;
        int tot = h0 + h1 + h2 + h3;
        int lane = t & 63;
        int scan = tot;
        #pragma unroll
        for (int off = 1; off < 64; off <<= 1) {
            int v = __shfl_up(scan, off);
            if (lane >= off) scan += v;
        }
        if (lane == 63) swt[t >> 6] = scan;
        __syncthreads();
        int wbase = 0;
        for (int i = 0; i < (t >> 6); ++i) wbase += swt[i];
        int excl = wbase + scan - tot;
        if (base + 0 < C) { offs[base + 0] = excl;                fillpos[base + 0] = excl; }
        if (base + 1 < C) { offs[base + 1] = excl + h0;           fillpos[base + 1] = excl + h0; }
        if (base + 2 < C) { offs[base + 2] = excl + h0 + h1;      fillpos[base + 2] = excl + h0 + h1; }
        if (base + 3 < C) { offs[base + 3] = excl + h0 + h1 + h2; fillpos[base + 3] = excl + h0 + h1 + h2; }
    }
}

// K3: scatter row ids of touched clusters into contiguous per-cluster lists.
__global__ __launch_bounds__(256) void fill_kernel(
    const int* __restrict__ labels, const int* __restrict__ touched,
    int* __restrict__ fillpos, int* __restrict__ rowlist)
{
    int i = blockIdx.x * 256 + threadIdx.x;
    if (i >= N) return;
    int lab = labels[i];
    if (touched[lab]) {
        int p = atomicAdd(&fillpos[lab], 1);
        rowlist[p] = i;
    }
}

// K4: cluster mean without reading out_feats: sum features rows and apply the
// winner correction:
//   sum = sum_{r in c} features[r] + sum_{winners w: lab_w==c} (new_rows[w] - features[row_w])
__global__ __launch_bounds__(1024) void cm_kernel(
    const float* __restrict__ cluster_mean, const float* __restrict__ features,
    const float* __restrict__ new_rows, const int* __restrict__ touched,
    const int* __restrict__ hist, const int* __restrict__ offs,
    const int* __restrict__ rowlist, const int* __restrict__ nw,
    const int* __restrict__ w_row, const int* __restrict__ w_lab,
    const int* __restrict__ w_b, float* __restrict__ out_cm)
{
    const int c = blockIdx.x;
    const int d = threadIdx.x & 255;
    const int k = threadIdx.x >> 8;     // 0..3
    if (!touched[c]) {                  // block-uniform branch
        if (k == 0) out_cm[(size_t)c * D + d] = cluster_mean[(size_t)c * D + d];
        return;
    }
    __shared__ float red[3][256];
    const int cnt = hist[c];
    const int off = offs[c];
    float acc = 0.0f;
    #pragma unroll 4
    for (int j = k; j < cnt; j += 4)
        acc += features[(size_t)rowlist[off + j] * D + d];
    // winner correction, distributed over k-chunks (block-uniform inner test)
    const int nwv = *nw;
    for (int j = k; j < nwv; j += 4) {
        if (w_lab[j] == c)
            acc += new_rows[w_b[j] * D + d] - features[(size_t)w_row[j] * D + d];
    }
    if (k > 0) red[k - 1][d] = acc;
    __syncthreads();
    if (k == 0) {
        float tot = acc + red[0][d] + red[1][d] + red[2][d];
        out_cm[(size_t)c * D + d] = tot / fmaxf((float)cnt, 1.0f);
    }
}

extern "C" void kernel_launch(void* const* d_in, const int* in_sizes, int n_in,
                              void* d_out, int out_size, void* d_ws, size_t ws_size,
                              hipStream_t stream) {
    const float* inputs       = (const float*)d_in[0];
    const float* features     = (const float*)d_in[1];
    const float* cluster_mean = (const float*)d_in[2];
    const int*   indexes      = (const int*)d_in[3];
    const int*   labels       = (const int*)d_in[4];
    const int*   targets      = (const int*)d_in[5];

    float* out_logits = (float*)d_out;                      // B*C
    float* out_feats  = out_logits + (size_t)B * C;         // N*D
    float* out_cm     = out_feats + (size_t)N * D;          // C*D

    char* ws = (char*)d_ws;
    float* new_rows = (float*)(ws + WS_NEWROWS_OFF);
    int*   hist     = (int*)(ws + WS_HIST_OFF);
    int*   touched  = (int*)(ws + WS_TOUCHED_OFF);
    int*   nw       = (int*)(ws + WS_NW_OFF);
    int*   offs     = (int*)(ws + WS_OFFS_OFF);
    int*   fillpos  = (int*)(ws + WS_FILLPOS_OFF);
    int*   w_row    = (int*)(ws + WS_WROW_OFF);
    int*   w_lab    = (int*)(ws + WS_WLAB_OFF);
    int*   w_b      = (int*)(ws + WS_WB_OFF);
    int*   rowlist  = (int*)(ws + WS_ROWLIST_OFF);

    k0_zero<<<(ZERO_WORDS + 255) / 256, 256, 0, stream>>>((int*)(ws + WS_HIST_OFF));
    k1_kernel<<<K1_BLOCKS, 256, 0, stream>>>(inputs, features, cluster_mean,
                                             indexes, labels, targets,
                                             out_logits, out_feats, new_rows,
                                             hist, touched);
    k2_kernel<<<257, 256, 0, stream>>>(indexes, labels, new_rows, out_feats,
                                       hist, offs, fillpos, nw, w_row, w_lab, w_b);
    fill_kernel<<<(N + 255) / 256, 256, 0, stream>>>(labels, touched, fillpos, rowlist);
    cm_kernel<<<C, 1024, 0, stream>>>(cluster_mean, features, new_rows, touched,
                                      hist, offs, rowlist, nw, w_row, w_lab, w_b,
                                      out_cm);
}